// Round 2
// baseline (18.456 us; speedup 1.0000x reference)
//
#include <hip/hip_runtime.h>
#include <hip/hip_bf16.h>
#include <stdint.h>

#define NPTS 8192
#define DIM  64
#define NB   4
#define KK   9
#define BQ   64       // queries per block (main kernel)
#define RROWS 160     // staged rows: global m = n0-89+r
#define SD2  72       // stage row stride in bf16 elems (144 B, 16B-aligned)
#define UD2  91       // key stride per query (uints): wofs 0..89 + pad
#define WS_NEED (NB * NPTS * DIM * 2 + NB * NPTS * 4)   // y bf16 + rn f32

typedef short bf16x8 __attribute__((ext_vector_type(8)));
typedef float f32x4  __attribute__((ext_vector_type(4)));

// ---------------- kernel 1: transpose + bf16 cast + inverse norms ----------------
// x[b][d][n] f32 -> y[b][n][d] bf16 (unnormalized, same bits as fused stage),
// rnG[b][n] = 1/max(sqrt(sum d x^2), eps), f32, summation order = 4 partials x 16 d.
__global__ __launch_bounds__(256, 4) void prep(const float* __restrict__ x,
                                               ushort* __restrict__ y,
                                               float* __restrict__ rnG) {
    __shared__ uint32_t st[64 * 36];   // bf16 pairs [n_local][d/2], stride 36 uints
    __shared__ float psum[256];

    const int tid = threadIdx.x;
    const int blk = blockIdx.x;
    const int b   = blk >> 7;              // 128 tiles per batch
    const int n0  = (blk & 127) << 6;      // 64 points per block
    const int nl  = tid & 63;
    const int dh  = (tid >> 6) << 4;       // 0,16,32,48

    const float* src = x + (size_t)b * DIM * NPTS + n0 + nl;
    float s = 0.f;
#pragma unroll
    for (int j = 0; j < 2; ++j) {
        uint32_t pk[4];
#pragma unroll
        for (int e = 0; e < 4; ++e) {
            int d = dh + j * 8 + e * 2;
            float v0 = src[(size_t)d * NPTS];
            float v1 = src[(size_t)(d + 1) * NPTS];
            s += v0 * v0 + v1 * v1;
            __hip_bfloat162 h2 = __float22bfloat162_rn(make_float2(v0, v1));
            pk[e] = *reinterpret_cast<uint32_t*>(&h2);
        }
        *reinterpret_cast<uint4*>(&st[nl * 36 + dh / 2 + j * 4]) =
            make_uint4(pk[0], pk[1], pk[2], pk[3]);
    }
    psum[tid] = s;
    __syncthreads();

    if (tid < 64) {
        float ss = psum[tid] + psum[tid + 64] + psum[tid + 128] + psum[tid + 192];
        rnG[(size_t)b * NPTS + n0 + tid] = 1.0f / fmaxf(sqrtf(ss), 1e-12f);
    }

    // write y rows: 512 chunks of 16 B, fully coalesced
    uint4* yv = (uint4*)(y + ((size_t)b * NPTS + n0) * DIM);
#pragma unroll
    for (int i = 0; i < 2; ++i) {
        int c = tid + 256 * i;
        int row = c >> 3, col = c & 7;
        yv[c] = *reinterpret_cast<const uint4*>(&st[row * 36 + col * 4]);
    }
}

// ---------------- kernel 2: banded Gram + key pack + top-9 extraction ----------------
// Stage = coalesced bf16 row copies; keys compacted to ud[q][wofs] (wofs = m-(n-89)).
__global__ __launch_bounds__(512, 4) void knn_core(const ushort* __restrict__ y,
                                                   const float* __restrict__ rnG,
                                                   int* __restrict__ out) {
    __shared__ ushort   sb[RROWS * SD2];   // 23040 B staged bf16 rows
    __shared__ uint32_t ud[BQ * UD2];      // 23296 B packed keys [q][wofs]
    __shared__ float    rnArr[RROWS];

    const int tid = threadIdx.x;
    // XCD-chunked swizzle: same-XCD blocks take consecutive tiles -> window L2 hits
    const int blk = blockIdx.x;
    const int L   = (blk & 7) * 64 + (blk >> 3);
    const int b   = L >> 7;
    const int n0  = (L & 127) << 6;
    const int gbase = n0 - 89;

    const ushort* yb = y + (size_t)b * NPTS * DIM;

    // ---- stage: 160 rows x 128 B, 16 B/lane coalesced ----
#pragma unroll
    for (int i = 0; i < 3; ++i) {
        int c = tid + 512 * i;
        if (c < RROWS * 8) {
            int row = c >> 3, col = c & 7;
            int m = gbase + row;
            bool ok = (m >= 0 && m < NPTS);
            const uint4* src =
                reinterpret_cast<const uint4*>(yb + (size_t)(ok ? m : 0) * DIM) + col;
            uint4 v = ok ? *src : make_uint4(0u, 0u, 0u, 0u);
            *reinterpret_cast<uint4*>(&sb[row * SD2 + col * 8]) = v;
        }
    }
    if (tid < RROWS) {
        int m = gbase + tid;
        rnArr[tid] = (m >= 0 && m < NPTS) ? rnG[(size_t)b * NPTS + m] : 1.0f;
    }
    __syncthreads();   // bar1: sb + rnArr visible

    const int w  = tid >> 6;
    const int l  = tid & 63;
    const int qt = w >> 1;            // query tile 0..3
    const int h  = w & 1;             // row-tile half
    const int lr = l & 15;
    const int lk = l >> 4;
    const int nrt = 4 - h;            // 4 or 3 row tiles (band rows 16qt .. 16qt+111)

    const ushort* ap = &sb[(size_t)(89 + qt * 16 + lr) * SD2 + lk * 8];
    bf16x8 a0 = *reinterpret_cast<const bf16x8*>(ap);
    bf16x8 a1 = *reinterpret_cast<const bf16x8*>(ap + 32);

    float rq[4];
#pragma unroll
    for (int j = 0; j < 4; ++j) rq[j] = rnArr[89 + qt * 16 + lk * 4 + j];
    const int q0 = qt * 16 + lk * 4;

    // ---- MFMA + key pack/write (sb and ud disjoint -> no barrier needed here) ----
#pragma unroll
    for (int i = 0; i < 4; ++i) {
        if (i < nrt) {
            const int rto = h * 4 + i;
            const int rbase = qt * 16 + rto * 16;
            const ushort* bp = &sb[(size_t)(rbase + lr) * SD2 + lk * 8];
            bf16x8 b0 = *reinterpret_cast<const bf16x8*>(bp);
            bf16x8 b1 = *reinterpret_cast<const bf16x8*>(bp + 32);
            f32x4 acc = {0.f, 0.f, 0.f, 0.f};
            acc = __builtin_amdgcn_mfma_f32_16x16x32_bf16(a0, b0, acc, 0, 0, 0);
            acc = __builtin_amdgcn_mfma_f32_16x16x32_bf16(a1, b1, acc, 0, 0, 0);
            const int r = rbase + lr;
            const float rnr = rnArr[r];
#pragma unroll
            for (int j = 0; j < 4; ++j) {
                int rel = r - (q0 + j);          // window offset
                if (rel >= 0 && rel <= 89) {
                    float p = acc[j] * rq[j] * rnr;
                    float dist = 2.0f - 2.0f * p;
                    uint32_t uu = __float_as_uint(dist);
                    uu = (uu & 0x80000000u) ? ~uu : (uu | 0x80000000u);
                    ud[(q0 + j) * UD2 + rel] = (uu & 0xFFFFFF80u) | (uint32_t)rel;
                }
            }
        }
    }
    __syncthreads();   // bar2: keys visible

    // ---- selection: 8 lanes per query, 9 rounds of masked-min extraction ----
    {
        const int ql = l >> 3;             // 0..7
        const int s  = l & 7;              // 0..7
        const int q  = (w << 3) | ql;      // 0..63
        const int n  = n0 + q;

        uint32_t key[12];
#pragma unroll
        for (int t = 0; t < 12; ++t) {
            int wofs = s + 8 * t;          // window offset 0..95
            int m = n - 89 + wofs;
            bool ok = (wofs <= 89) && (m >= 0);
            uint32_t raw = ud[q * UD2 + (ok ? wofs : 0)];
            key[t] = ok ? raw : 0xFFFFFFFFu;
        }

        uint32_t prev = 0;
        int omKeep = n;
        int om8 = n;
#pragma unroll
        for (int j = 0; j < KK; ++j) {
            uint32_t mn = 0xFFFFFFFFu;
#pragma unroll
            for (int t = 0; t < 12; ++t) {
                uint32_t cand = (key[t] > prev) ? key[t] : 0xFFFFFFFFu;
                mn = (cand < mn) ? cand : mn;
            }
            uint32_t o;
            o = (uint32_t)__shfl_xor((int)mn, 1); mn = (o < mn) ? o : mn;
            o = (uint32_t)__shfl_xor((int)mn, 2); mn = (o < mn) ? o : mn;
            o = (uint32_t)__shfl_xor((int)mn, 4); mn = (o < mn) ? o : mn;
            int om = (mn == 0xFFFFFFFFu) ? n : (n - 89 + (int)(mn & 127u));
            if (j < 8) {
                if (s == j) omKeep = om;
            } else {
                om8 = om;
            }
            prev = mn;
        }

        const int base0 = (b * NPTS + n) * KK;
        const int base1 = NB * NPTS * KK + base0;
        out[base0 + s] = omKeep;
        out[base1 + s] = n;
        if (s == 0) {
            out[base0 + 8] = om8;
            out[base1 + 8] = n;
        }
    }
}

// ---------------- fallback: round-1 monolithic kernel (used if ws too small) ----------------
#define UDF 65
__global__ __launch_bounds__(512, 4) void knn_fused(const float* __restrict__ x,
                                                    int* __restrict__ out) {
    __shared__ uint32_t ud[RROWS * UDF];
    __shared__ ushort   sb[RROWS * SD2];
    __shared__ float    rnArr[RROWS];

    float* psumA = (float*)ud;
    float* psumB = (float*)ud + 512;

    const int tid = threadIdx.x;
    const int blk = blockIdx.x;
    const int L   = (blk & 7) * 64 + (blk >> 3);
    const int b   = L >> 7;
    const int n0  = (L & 127) << 6;
    const int gbase = n0 - 89;

    const float* xb = x + (size_t)b * DIM * NPTS;

    {
        const int g  = tid & 127;
        const int dh = (tid >> 7) << 4;
        const int gg = gbase + g;
        const bool ok = (gg >= 0 && gg < NPTS);
        const float* src = xb + (ok ? gg : 0);
        float s = 0.f;
#pragma unroll
        for (int j = 0; j < 2; ++j) {
            uint32_t pk[4];
#pragma unroll
            for (int e = 0; e < 4; ++e) {
                int d = dh + j * 8 + e * 2;
                float v0 = ok ? src[(size_t)d * NPTS] : 0.f;
                float v1 = ok ? src[(size_t)(d + 1) * NPTS] : 0.f;
                s += v0 * v0 + v1 * v1;
                __hip_bfloat162 h2 = __float22bfloat162_rn(make_float2(v0, v1));
                pk[e] = *reinterpret_cast<uint32_t*>(&h2);
            }
            *reinterpret_cast<uint4*>(&sb[(size_t)g * SD2 + dh + j * 8]) =
                make_uint4(pk[0], pk[1], pk[2], pk[3]);
        }
        psumA[tid] = s;
    }
    {
        const int g  = 128 + (tid & 31);
        const int c  = tid >> 5;
        const int gg = gbase + g;
        const bool ok = (gg >= 0 && gg < NPTS);
        const float* src = xb + (ok ? gg : 0);
        float s = 0.f;
        uint32_t pk[2];
#pragma unroll
        for (int e = 0; e < 2; ++e) {
            int d = c * 4 + e * 2;
            float v0 = ok ? src[(size_t)d * NPTS] : 0.f;
            float v1 = ok ? src[(size_t)(d + 1) * NPTS] : 0.f;
            s += v0 * v0 + v1 * v1;
            __hip_bfloat162 h2 = __float22bfloat162_rn(make_float2(v0, v1));
            pk[e] = *reinterpret_cast<uint32_t*>(&h2);
        }
        *reinterpret_cast<uint2*>(&sb[(size_t)g * SD2 + c * 4]) = make_uint2(pk[0], pk[1]);
        psumB[tid] = s;
    }
    __syncthreads();

    const int w  = tid >> 6;
    const int l  = tid & 63;
    const int qt = w >> 1;
    const int h  = w & 1;
    const int lr = l & 15;
    const int lk = l >> 4;
    const int nrt = 4 - h;

    const ushort* ap = &sb[(size_t)(89 + qt * 16 + lr) * SD2 + lk * 8];
    bf16x8 a0 = *reinterpret_cast<const bf16x8*>(ap);
    bf16x8 a1 = *reinterpret_cast<const bf16x8*>(ap + 32);
    bf16x8 bfr[4][2];
#pragma unroll
    for (int i = 0; i < 4; ++i) {
        if (i < nrt) {
            const int rto = h * 4 + i;
            const ushort* bp = &sb[(size_t)(qt * 16 + rto * 16 + lr) * SD2 + lk * 8];
            bfr[i][0] = *reinterpret_cast<const bf16x8*>(bp);
            bfr[i][1] = *reinterpret_cast<const bf16x8*>(bp + 32);
        }
    }

    if (tid < 128) {
        float s = psumA[tid] + psumA[tid + 128] + psumA[tid + 256] + psumA[tid + 384];
        rnArr[tid] = 1.0f / fmaxf(sqrtf(s), 1e-12f);
    } else if (tid < 160) {
        int rr = tid - 128;
        float s = 0.f;
#pragma unroll
        for (int k = 0; k < 16; ++k) s += psumB[rr + 32 * k];
        rnArr[tid] = 1.0f / fmaxf(sqrtf(s), 1e-12f);
    }
    __syncthreads();

    {
        float rq[4];
#pragma unroll
        for (int j = 0; j < 4; ++j) rq[j] = rnArr[89 + qt * 16 + lk * 4 + j];
        const int q0 = qt * 16 + lk * 4;
#pragma unroll
        for (int i = 0; i < 4; ++i) {
            if (i < nrt) {
                f32x4 acc = {0.f, 0.f, 0.f, 0.f};
                acc = __builtin_amdgcn_mfma_f32_16x16x32_bf16(a0, bfr[i][0], acc, 0, 0, 0);
                acc = __builtin_amdgcn_mfma_f32_16x16x32_bf16(a1, bfr[i][1], acc, 0, 0, 0);
                const int rto = h * 4 + i;
                const int r = qt * 16 + rto * 16 + lr;
                const float rnr = rnArr[r];
#pragma unroll
                for (int j = 0; j < 4; ++j) {
                    float p = acc[j] * rq[j] * rnr;
                    float dist = 2.0f - 2.0f * p;
                    uint32_t uu = __float_as_uint(dist);
                    uu = (uu & 0x80000000u) ? ~uu : (uu | 0x80000000u);
                    int rel = r - (q0 + j);
                    ud[r * UDF + q0 + j] = (uu & 0xFFFFFF80u) | ((uint32_t)rel & 127u);
                }
            }
        }
    }
    __syncthreads();

    {
        const int ql = l >> 3;
        const int s  = l & 7;
        const int q  = (w << 3) | ql;
        const int n  = n0 + q;

        uint32_t key[12];
#pragma unroll
        for (int t = 0; t < 12; ++t) {
            int wofs = s + 8 * t;
            int m = n - 89 + wofs;
            bool ok = (wofs <= 89) && (m >= 0);
            int r = q + (ok ? wofs : 0);
            uint32_t raw = ud[r * UDF + q];
            key[t] = ok ? raw : 0xFFFFFFFFu;
        }

        uint32_t prev = 0;
        int omKeep = n;
        int om8 = n;
#pragma unroll
        for (int j = 0; j < KK; ++j) {
            uint32_t mn = 0xFFFFFFFFu;
#pragma unroll
            for (int t = 0; t < 12; ++t) {
                uint32_t cand = (key[t] > prev) ? key[t] : 0xFFFFFFFFu;
                mn = (cand < mn) ? cand : mn;
            }
            uint32_t o;
            o = (uint32_t)__shfl_xor((int)mn, 1); mn = (o < mn) ? o : mn;
            o = (uint32_t)__shfl_xor((int)mn, 2); mn = (o < mn) ? o : mn;
            o = (uint32_t)__shfl_xor((int)mn, 4); mn = (o < mn) ? o : mn;
            int om = (mn == 0xFFFFFFFFu) ? n : (n - 89 + (int)(mn & 127u));
            if (j < 8) {
                if (s == j) omKeep = om;
            } else {
                om8 = om;
            }
            prev = mn;
        }

        const int base0 = (b * NPTS + n) * KK;
        const int base1 = NB * NPTS * KK + base0;
        out[base0 + s] = omKeep;
        out[base1 + s] = n;
        if (s == 0) {
            out[base0 + 8] = om8;
            out[base1 + 8] = n;
        }
    }
}

extern "C" void kernel_launch(void* const* d_in, const int* in_sizes, int n_in,
                              void* d_out, int out_size, void* d_ws, size_t ws_size,
                              hipStream_t stream) {
    const float* x = (const float*)d_in[0];
    int* out = (int*)d_out;
    if (d_ws != nullptr && ws_size >= (size_t)WS_NEED) {
        ushort* y   = (ushort*)d_ws;
        float*  rnG = (float*)((char*)d_ws + (size_t)NB * NPTS * DIM * 2);
        prep<<<NB * (NPTS / 64), 256, 0, stream>>>(x, y, rnG);
        knn_core<<<NB * (NPTS / BQ), 512, 0, stream>>>(y, rnG, out);
    } else {
        knn_fused<<<NB * (NPTS / BQ), 512, 0, stream>>>(x, out);
    }
}

// Round 3
// 15.616 us; speedup vs baseline: 1.1819x; 1.1819x over previous
//
#include <hip/hip_runtime.h>
#include <hip/hip_bf16.h>
#include <stdint.h>

#define NPTS 8192
#define DIM  64
#define NB   4
#define KK   9
#define BQ   64       // queries per block
#define RROWS 160     // staged rows: global m = n0-89+r, r in [0,159]; rows [0,152] used
#define SD2  72       // stage row stride in bf16 elems (144 B, 16B-aligned)
#define UD2  91       // key stride per query (uints): wofs 0..89 + pad

typedef short bf16x8 __attribute__((ext_vector_type(8)));
typedef float f32x4  __attribute__((ext_vector_type(4)));

// Monolithic fused KNN, 2-barrier schedule:
//   stage bf16 (transpose) + in-wave shuffle norms -> bar1 ->
//   banded MFMA Gram + compact key pack (sb/ud disjoint, no barrier) -> bar2 ->
//   8-lane/query top-9 min-extraction.
// Query q (global n = n0+q) is staged row q+89; candidate m = n-89+wofs is row q+wofs.
__global__ __launch_bounds__(512, 4) void knn_fused(const float* __restrict__ x,
                                                    int* __restrict__ out) {
    __shared__ ushort   sb[RROWS * SD2];   // 23040 B staged bf16 rows
    __shared__ uint32_t ud[BQ * UD2];      // 23296 B packed keys [q][wofs]
    __shared__ float    rnArr[RROWS];      // 640 B inverse norms

    const int tid = threadIdx.x;
    // XCD-chunked swizzle: same-XCD blocks take consecutive tiles -> window L2 hits
    const int blk = blockIdx.x;
    const int L   = (blk & 7) * 64 + (blk >> 3);   // bijective on 512 blocks
    const int b   = L >> 7;                        // 128 tiles per batch
    const int n0  = (L & 127) << 6;
    const int gbase = n0 - 89;

    const float* xb = x + (size_t)b * DIM * NPTS;

    // ---- stage region 1: rows 0..127, 4 adjacent lanes/row x 16 dims ----
    {
        const int g    = tid >> 2;                 // row 0..127
        const int part = tid & 3;                  // dim quarter (same wave!)
        const int gg   = gbase + g;
        const bool ok  = (gg >= 0 && gg < NPTS);
        const float* src = xb + (ok ? gg : 0);
        float s = 0.f;
#pragma unroll
        for (int j = 0; j < 2; ++j) {
            uint32_t pk[4];
#pragma unroll
            for (int e = 0; e < 4; ++e) {
                int d = part * 16 + j * 8 + e * 2;
                float v0 = ok ? src[(size_t)d * NPTS] : 0.f;
                float v1 = ok ? src[(size_t)(d + 1) * NPTS] : 0.f;
                s += v0 * v0 + v1 * v1;
                __hip_bfloat162 h2 = __float22bfloat162_rn(make_float2(v0, v1));
                pk[e] = *reinterpret_cast<uint32_t*>(&h2);
            }
            *reinterpret_cast<uint4*>(&sb[(size_t)g * SD2 + part * 16 + j * 8]) =
                make_uint4(pk[0], pk[1], pk[2], pk[3]);
        }
        // in-wave row-norm reduce over the 4 dim-quarters
        s += __shfl_xor(s, 1);
        s += __shfl_xor(s, 2);
        if (part == 0) rnArr[g] = 1.0f / fmaxf(sqrtf(s), 1e-12f);
    }
    // ---- stage region 2: rows 128..159, 16 adjacent lanes/row x 4 dims ----
    {
        const int g   = 128 + (tid >> 4);          // row 128..159
        const int p16 = tid & 15;                  // dim sixteenth (same wave)
        const int gg  = gbase + g;
        const bool ok = (gg >= 0 && gg < NPTS);
        const float* src = xb + (ok ? gg : 0);
        float s = 0.f;
        uint32_t pk[2];
#pragma unroll
        for (int e = 0; e < 2; ++e) {
            int d = p16 * 4 + e * 2;
            float v0 = ok ? src[(size_t)d * NPTS] : 0.f;
            float v1 = ok ? src[(size_t)(d + 1) * NPTS] : 0.f;
            s += v0 * v0 + v1 * v1;
            __hip_bfloat162 h2 = __float22bfloat162_rn(make_float2(v0, v1));
            pk[e] = *reinterpret_cast<uint32_t*>(&h2);
        }
        *reinterpret_cast<uint2*>(&sb[(size_t)g * SD2 + p16 * 4]) = make_uint2(pk[0], pk[1]);
        s += __shfl_xor(s, 1);
        s += __shfl_xor(s, 2);
        s += __shfl_xor(s, 4);
        s += __shfl_xor(s, 8);
        if (p16 == 0) rnArr[g] = 1.0f / fmaxf(sqrtf(s), 1e-12f);
    }
    __syncthreads();   // bar1: sb + rnArr visible

    // ---- banded MFMA Gram + compact key pack (no barrier needed: ud/sb disjoint) ----
    const int w  = tid >> 6;
    const int l  = tid & 63;
    const int qt = w >> 1;            // query tile 0..3
    const int h  = w & 1;             // row-tile half
    const int lr = l & 15;
    const int lk = l >> 4;
    const int nrt = 4 - h;            // 4 or 3 row tiles (band rows 16qt .. 16qt+111)

    const ushort* ap = &sb[(size_t)(89 + qt * 16 + lr) * SD2 + lk * 8];
    bf16x8 a0 = *reinterpret_cast<const bf16x8*>(ap);
    bf16x8 a1 = *reinterpret_cast<const bf16x8*>(ap + 32);

    float rq[4];
#pragma unroll
    for (int j = 0; j < 4; ++j) rq[j] = rnArr[89 + qt * 16 + lk * 4 + j];
    const int q0 = qt * 16 + lk * 4;

#pragma unroll
    for (int i = 0; i < 4; ++i) {
        if (i < nrt) {
            const int rto = h * 4 + i;
            const int rbase = qt * 16 + rto * 16;
            const ushort* bp = &sb[(size_t)(rbase + lr) * SD2 + lk * 8];
            bf16x8 b0 = *reinterpret_cast<const bf16x8*>(bp);
            bf16x8 b1 = *reinterpret_cast<const bf16x8*>(bp + 32);
            f32x4 acc = {0.f, 0.f, 0.f, 0.f};
            acc = __builtin_amdgcn_mfma_f32_16x16x32_bf16(a0, b0, acc, 0, 0, 0);
            acc = __builtin_amdgcn_mfma_f32_16x16x32_bf16(a1, b1, acc, 0, 0, 0);
            const int r = rbase + lr;
            const float rnr = rnArr[r];
#pragma unroll
            for (int j = 0; j < 4; ++j) {
                int rel = r - (q0 + j);            // window offset
                if (rel >= 0 && rel <= 89) {
                    float p = acc[j] * rq[j] * rnr;
                    float dist = 2.0f - 2.0f * p;
                    uint32_t uu = __float_as_uint(dist);
                    uu = (uu & 0x80000000u) ? ~uu : (uu | 0x80000000u);
                    ud[(q0 + j) * UD2 + rel] = (uu & 0xFFFFFF80u) | (uint32_t)rel;
                }
            }
        }
    }
    __syncthreads();   // bar2: keys visible

    // ---- selection: 8 lanes per query, 9 rounds of masked-min extraction ----
    {
        const int ql = l >> 3;             // 0..7
        const int s  = l & 7;              // 0..7
        const int q  = (w << 3) | ql;      // 0..63
        const int n  = n0 + q;

        uint32_t key[12];
#pragma unroll
        for (int t = 0; t < 12; ++t) {
            int wofs = s + 8 * t;          // window offset 0..95
            int m = n - 89 + wofs;
            bool ok = (wofs <= 89) && (m >= 0);
            uint32_t raw = ud[q * UD2 + (ok ? wofs : 0)];
            key[t] = ok ? raw : 0xFFFFFFFFu;
        }

        uint32_t prev = 0;
        int omKeep = n;
        int om8 = n;
#pragma unroll
        for (int j = 0; j < KK; ++j) {
            uint32_t mn = 0xFFFFFFFFu;
#pragma unroll
            for (int t = 0; t < 12; ++t) {
                uint32_t cand = (key[t] > prev) ? key[t] : 0xFFFFFFFFu;
                mn = (cand < mn) ? cand : mn;
            }
            uint32_t o;
            o = (uint32_t)__shfl_xor((int)mn, 1); mn = (o < mn) ? o : mn;
            o = (uint32_t)__shfl_xor((int)mn, 2); mn = (o < mn) ? o : mn;
            o = (uint32_t)__shfl_xor((int)mn, 4); mn = (o < mn) ? o : mn;
            int om = (mn == 0xFFFFFFFFu) ? n : (n - 89 + (int)(mn & 127u));
            if (j < 8) {
                if (s == j) omKeep = om;
            } else {
                om8 = om;
            }
            prev = mn;
        }

        const int base0 = (b * NPTS + n) * KK;
        const int base1 = NB * NPTS * KK + base0;
        out[base0 + s] = omKeep;           // 8 coalesced lanes per query
        out[base1 + s] = n;
        if (s == 0) {
            out[base0 + 8] = om8;
            out[base1 + 8] = n;
        }
    }
}

extern "C" void kernel_launch(void* const* d_in, const int* in_sizes, int n_in,
                              void* d_out, int out_size, void* d_ws, size_t ws_size,
                              hipStream_t stream) {
    const float* x = (const float*)d_in[0];
    int* out = (int*)d_out;
    knn_fused<<<NB * (NPTS / BQ), 512, 0, stream>>>(x, out);
}

// Round 4
// 14.748 us; speedup vs baseline: 1.2515x; 1.0589x over previous
//
#include <hip/hip_runtime.h>
#include <hip/hip_bf16.h>
#include <stdint.h>

#define NPTS 8192
#define DIM  64
#define NB   4
#define KK   9
#define BQ   64       // queries per block
#define RROWS 160     // staged rows: global m = n0-89+r, r in [0,159]; rows [0,152] used
#define SD2  72       // stage row stride in bf16 elems (144 B, 16B-aligned)
#define UD2  91       // key stride per query (uints): wofs 0..89 + pad

typedef short bf16x8 __attribute__((ext_vector_type(8)));
typedef float f32x4  __attribute__((ext_vector_type(4)));

// 2-barrier fused KNN:
//   stage bf16 (R1 coalesced mapping) + f32 psum -> bar1 ->
//   frag prefetch || psum reduce -> bar2 ->
//   per-wave full-band MFMA + own-8-query key pack -> (same-wave lgkm only) ->
//   8-lane/query top-9 min-extraction.
// Query q (global n = n0+q) is staged row q+89; candidate m = n-89+wofs is row q+wofs.
// Wave w owns queries 8w..8w+7 (qtile w>>1, half w&1) end-to-end: pack guard
// lk>>1 == w&1 means selection reads only this wave's own ds_writes -> no bar3.
__global__ __launch_bounds__(512, 4) void knn_fused(const float* __restrict__ x,
                                                    int* __restrict__ out) {
    __shared__ uint32_t ud[BQ * UD2];      // 23296 B keys [q][wofs]; head doubles as psum
    __shared__ ushort   sb[RROWS * SD2];   // 23040 B staged bf16 rows
    __shared__ float    rnArr[RROWS];      // 640 B inverse norms

    float* psumA = (float*)ud;             // [512] partials rows 0..127
    float* psumB = (float*)ud + 512;       // [512] partials rows 128..159

    const int tid = threadIdx.x;
    // XCD-chunked swizzle: same-XCD blocks take consecutive tiles -> window L2 hits
    const int blk = blockIdx.x;
    const int L   = (blk & 7) * 64 + (blk >> 3);   // bijective on 512 blocks
    const int b   = L >> 7;                        // 128 tiles per batch
    const int n0  = (L & 127) << 6;
    const int gbase = n0 - 89;

    const float* xb = x + (size_t)b * DIM * NPTS;

    // ---- stage region 1: rows 0..127, 4 partial-threads/row x 16 dims ----
    // (lanes 0..63 of each wave read 64 CONSECUTIVE columns at fixed d: 256 B/segment)
    {
        const int g  = tid & 127;
        const int dh = (tid >> 7) << 4;            // 0,16,32,48
        const int gg = gbase + g;
        const bool ok = (gg >= 0 && gg < NPTS);
        const float* src = xb + (ok ? gg : 0);
        float s = 0.f;
#pragma unroll
        for (int j = 0; j < 2; ++j) {
            uint32_t pk[4];
#pragma unroll
            for (int e = 0; e < 4; ++e) {
                int d = dh + j * 8 + e * 2;
                float v0 = ok ? src[(size_t)d * NPTS] : 0.f;
                float v1 = ok ? src[(size_t)(d + 1) * NPTS] : 0.f;
                s += v0 * v0 + v1 * v1;
                __hip_bfloat162 h2 = __float22bfloat162_rn(make_float2(v0, v1));
                pk[e] = *reinterpret_cast<uint32_t*>(&h2);
            }
            *reinterpret_cast<uint4*>(&sb[(size_t)g * SD2 + dh + j * 8]) =
                make_uint4(pk[0], pk[1], pk[2], pk[3]);
        }
        psumA[tid] = s;
    }
    // ---- stage region 2: rows 128..159, 16 partial-threads/row x 4 dims ----
    {
        const int g  = 128 + (tid & 31);
        const int c  = tid >> 5;                   // 0..15
        const int gg = gbase + g;
        const bool ok = (gg >= 0 && gg < NPTS);
        const float* src = xb + (ok ? gg : 0);
        float s = 0.f;
        uint32_t pk[2];
#pragma unroll
        for (int e = 0; e < 2; ++e) {
            int d = c * 4 + e * 2;
            float v0 = ok ? src[(size_t)d * NPTS] : 0.f;
            float v1 = ok ? src[(size_t)(d + 1) * NPTS] : 0.f;
            s += v0 * v0 + v1 * v1;
            __hip_bfloat162 h2 = __float22bfloat162_rn(make_float2(v0, v1));
            pk[e] = *reinterpret_cast<uint32_t*>(&h2);
        }
        *reinterpret_cast<uint2*>(&sb[(size_t)g * SD2 + c * 4]) = make_uint2(pk[0], pk[1]);
        psumB[tid] = s;
    }
    __syncthreads();   // bar1: sb + psum visible

    // ---- A-frag prefetch (sb valid) overlapped with inverse-norm reduce ----
    const int w  = tid >> 6;
    const int l  = tid & 63;
    const int qt = w >> 1;            // query tile 0..3 (each owned by a wave PAIR)
    const int lr = l & 15;
    const int lk = l >> 4;
    const bool packHalf = ((lk >> 1) == (w & 1));   // this wave packs queries 8w..8w+7

    const ushort* ap = &sb[(size_t)(89 + qt * 16 + lr) * SD2 + lk * 8];
    bf16x8 a0 = *reinterpret_cast<const bf16x8*>(ap);
    bf16x8 a1 = *reinterpret_cast<const bf16x8*>(ap + 32);

    if (tid < 128) {
        float s = psumA[tid] + psumA[tid + 128] + psumA[tid + 256] + psumA[tid + 384];
        rnArr[tid] = 1.0f / fmaxf(sqrtf(s), 1e-12f);
    } else if (tid < 160) {
        int rr = tid - 128;
        float s = 0.f;
#pragma unroll
        for (int k = 0; k < 16; ++k) s += psumB[rr + 32 * k];
        rnArr[tid] = 1.0f / fmaxf(sqrtf(s), 1e-12f);
    }
    __syncthreads();   // bar2: rnArr visible; psum dead (ud writes now safe)

    // ---- per-wave full-band MFMA + own-half key pack (no barrier after) ----
    {
        float rq[4];
#pragma unroll
        for (int j = 0; j < 4; ++j) rq[j] = rnArr[89 + qt * 16 + lk * 4 + j];
        const int q0 = qt * 16 + lk * 4;
#pragma unroll
        for (int rto = 0; rto < 7; ++rto) {
            const int rbase = qt * 16 + rto * 16;
            const ushort* bp = &sb[(size_t)(rbase + lr) * SD2 + lk * 8];
            bf16x8 b0 = *reinterpret_cast<const bf16x8*>(bp);
            bf16x8 b1 = *reinterpret_cast<const bf16x8*>(bp + 32);
            f32x4 acc = {0.f, 0.f, 0.f, 0.f};
            acc = __builtin_amdgcn_mfma_f32_16x16x32_bf16(a0, b0, acc, 0, 0, 0);
            acc = __builtin_amdgcn_mfma_f32_16x16x32_bf16(a1, b1, acc, 0, 0, 0);
            const int r = rbase + lr;
            const float rnr = rnArr[r];
            if (packHalf) {
#pragma unroll
                for (int j = 0; j < 4; ++j) {
                    int rel = r - (q0 + j);          // window offset
                    if (rel >= 0 && rel <= 89) {
                        float p = acc[j] * rq[j] * rnr;
                        float dist = 2.0f - 2.0f * p;
                        uint32_t uu = __float_as_uint(dist);
                        uu = (uu & 0x80000000u) ? ~uu : (uu | 0x80000000u);
                        ud[(q0 + j) * UD2 + rel] = (uu & 0xFFFFFF80u) | (uint32_t)rel;
                    }
                }
            }
        }
    }
    // NO __syncthreads: selection below reads only keys THIS wave wrote;
    // compiler's lgkmcnt wait orders same-wave ds_write -> ds_read.

    // ---- selection: 8 lanes per query, 9 rounds of masked-min extraction ----
    {
        const int ql = l >> 3;             // 0..7
        const int s  = l & 7;              // 0..7
        const int q  = (w << 3) | ql;      // 0..63 (== this wave's packed queries)
        const int n  = n0 + q;

        uint32_t key[12];
#pragma unroll
        for (int t = 0; t < 12; ++t) {
            int wofs = s + 8 * t;          // window offset 0..95
            int m = n - 89 + wofs;
            bool ok = (wofs <= 89) && (m >= 0);
            uint32_t raw = ud[q * UD2 + (ok ? wofs : 0)];
            key[t] = ok ? raw : 0xFFFFFFFFu;
        }

        uint32_t prev = 0;
        int omKeep = n;
        int om8 = n;
#pragma unroll
        for (int j = 0; j < KK; ++j) {
            uint32_t mn = 0xFFFFFFFFu;
#pragma unroll
            for (int t = 0; t < 12; ++t) {
                uint32_t cand = (key[t] > prev) ? key[t] : 0xFFFFFFFFu;
                mn = (cand < mn) ? cand : mn;
            }
            uint32_t o;
            o = (uint32_t)__shfl_xor((int)mn, 1); mn = (o < mn) ? o : mn;
            o = (uint32_t)__shfl_xor((int)mn, 2); mn = (o < mn) ? o : mn;
            o = (uint32_t)__shfl_xor((int)mn, 4); mn = (o < mn) ? o : mn;
            int om = (mn == 0xFFFFFFFFu) ? n : (n - 89 + (int)(mn & 127u));
            if (j < 8) {
                if (s == j) omKeep = om;
            } else {
                om8 = om;
            }
            prev = mn;
        }

        const int base0 = (b * NPTS + n) * KK;
        const int base1 = NB * NPTS * KK + base0;
        out[base0 + s] = omKeep;           // 8 coalesced lanes per query
        out[base1 + s] = n;
        if (s == 0) {
            out[base0 + 8] = om8;
            out[base1 + 8] = n;
        }
    }
}

extern "C" void kernel_launch(void* const* d_in, const int* in_sizes, int n_in,
                              void* d_out, int out_size, void* d_ws, size_t ws_size,
                              hipStream_t stream) {
    const float* x = (const float*)d_in[0];
    int* out = (int*)d_out;
    knn_fused<<<NB * (NPTS / BQ), 512, 0, stream>>>(x, out);
}

// Round 5
// 13.307 us; speedup vs baseline: 1.3869x; 1.1082x over previous
//
#include <hip/hip_runtime.h>
#include <hip/hip_bf16.h>
#include <stdint.h>

#define NPTS 8192
#define DIM  64
#define NB   4
#define KK   9
#define BQ   64       // queries per block
#define RROWS 160     // staged rows: m = n0-90+r (row 0 = pad so gbase is EVEN)
#define SD2  72       // stage row stride in bf16 elems (144 B, 16B-aligned)
#define UD2  91       // key stride per query (uints): wofs 0..89 + pad

typedef short bf16x8 __attribute__((ext_vector_type(8)));
typedef float f32x4  __attribute__((ext_vector_type(4)));

// 3-barrier fused KNN (R1 structure), float2 stage, unmasked clamped loads,
// compact ud[q][wofs] keys.
//   stage bf16 (pair loads) + float2 psum -> bar1 ->
//   A-frag prefetch || psum reduce -> bar2 ->
//   banded MFMA (nrt split) + key pack -> bar3 -> 8-lane/query top-9 extraction.
// Row r <-> point m = n0-90+r. Query q (n = n0+q) = row q+90.
// Window candidate m = n-89+wofs = row q+1+wofs, wofs in [0,89]; rel = r-q-1.
// Garbage-safety: rows with m<0 or m>=NPTS are staged unmasked (clamped addr);
// their keys are either never packed (rel out of [0,89]) or masked to MAX in
// selection (m<0 check) - so no load masking is needed anywhere.
__global__ __launch_bounds__(512, 4) void knn_fused(const float* __restrict__ x,
                                                    int* __restrict__ out) {
    __shared__ uint32_t ud[BQ * UD2];      // 23296 B keys [q][wofs]; head doubles as psum
    __shared__ ushort   sb[RROWS * SD2];   // 23040 B staged bf16 rows
    __shared__ float    rnArr[RROWS];      // 640 B inverse norms

    float2* psumA = (float2*)ud;           // [512] row-pair partials (region 1)
    float2* psumB = (float2*)ud + 512;     // [128] = 8 waves x 16 row-pair partials (reg 2)

    const int tid = threadIdx.x;
    // XCD-chunked swizzle: same-XCD blocks take consecutive tiles -> window L2 hits
    const int blk = blockIdx.x;
    const int L   = (blk & 7) * 64 + (blk >> 3);   // bijective on 512 blocks
    const int b   = L >> 7;                        // 128 tiles per batch
    const int n0  = (L & 127) << 6;
    const int gbase = n0 - 90;                     // EVEN

    const float* xb = x + (size_t)b * DIM * NPTS;

    const int w = tid >> 6;
    const int l = tid & 63;

    // ---- stage region 1: rows 0..127 as 64 lane-pairs; wave w covers d in [8w,8w+7] ----
    // Each float2 load: 64 lanes x 8 B consecutive n -> 512 B contiguous segment.
    {
        const int g2 = l * 2;                      // row pair (g2, g2+1)
        const int gg = gbase + g2;
        const int gs = (gg < 0) ? 0 : gg;          // clamp only; no value masking
        const float* src = xb + gs;
        float s0 = 0.f, s1 = 0.f;
        uint32_t pkA[4], pkB[4];
#pragma unroll
        for (int e = 0; e < 4; ++e) {
            const int d = 8 * w + 2 * e;
            float2 v = *reinterpret_cast<const float2*>(&src[(size_t)d * NPTS]);
            float2 u = *reinterpret_cast<const float2*>(&src[(size_t)(d + 1) * NPTS]);
            s0 += v.x * v.x + u.x * u.x;
            s1 += v.y * v.y + u.y * u.y;
            __hip_bfloat162 hA = __float22bfloat162_rn(make_float2(v.x, u.x));
            __hip_bfloat162 hB = __float22bfloat162_rn(make_float2(v.y, u.y));
            pkA[e] = *reinterpret_cast<uint32_t*>(&hA);
            pkB[e] = *reinterpret_cast<uint32_t*>(&hB);
        }
        *reinterpret_cast<uint4*>(&sb[(size_t)g2 * SD2 + 8 * w]) =
            make_uint4(pkA[0], pkA[1], pkA[2], pkA[3]);
        *reinterpret_cast<uint4*>(&sb[(size_t)(g2 + 1) * SD2 + 8 * w]) =
            make_uint4(pkB[0], pkB[1], pkB[2], pkB[3]);
        psumA[tid] = make_float2(s0, s1);
    }
    // ---- stage region 2: rows 128..159 as 16 lane-pairs x 32 d-pairs ----
    {
        const int g2 = 128 + (l & 15) * 2;
        const int c  = (w << 2) | (l >> 4);        // 0..31: d pair (2c, 2c+1)
        const int gg = gbase + g2;                 // >= 38 always
        const int gs = (gg > NPTS - 2) ? (NPTS - 2) : gg;
        const float* src = xb + gs;
        float2 v = *reinterpret_cast<const float2*>(&src[(size_t)(2 * c) * NPTS]);
        float2 u = *reinterpret_cast<const float2*>(&src[(size_t)(2 * c + 1) * NPTS]);
        float s0 = v.x * v.x + u.x * u.x;
        float s1 = v.y * v.y + u.y * u.y;
        __hip_bfloat162 hA = __float22bfloat162_rn(make_float2(v.x, u.x));
        __hip_bfloat162 hB = __float22bfloat162_rn(make_float2(v.y, u.y));
        *reinterpret_cast<uint32_t*>(&sb[(size_t)g2 * SD2 + 2 * c]) =
            *reinterpret_cast<uint32_t*>(&hA);
        *reinterpret_cast<uint32_t*>(&sb[(size_t)(g2 + 1) * SD2 + 2 * c]) =
            *reinterpret_cast<uint32_t*>(&hB);
        // in-wave pre-reduce over the 4 c-values sharing this row pair (lanes l, l^16, l^32)
        s0 += __shfl_xor(s0, 16); s0 += __shfl_xor(s0, 32);
        s1 += __shfl_xor(s1, 16); s1 += __shfl_xor(s1, 32);
        if (l < 16) psumB[w * 16 + l] = make_float2(s0, s1);
    }
    __syncthreads();   // bar1: sb + psum visible

    // ---- A-frag prefetch (sb valid) overlapped with inverse-norm reduce ----
    const int qt = w >> 1;            // query tile 0..3
    const int h  = w & 1;             // row-tile half
    const int lr = l & 15;
    const int lk = l >> 4;
    const int nrt = 4 - h;            // 4 or 3 row tiles (band rows 16qt .. 16qt+111)

    const ushort* ap = &sb[(size_t)(90 + qt * 16 + lr) * SD2 + lk * 8];
    bf16x8 a0 = *reinterpret_cast<const bf16x8*>(ap);
    bf16x8 a1 = *reinterpret_cast<const bf16x8*>(ap + 32);

    if (tid < 128) {
        const int gp = tid >> 1, comp = tid & 1;
        float s = 0.f;
#pragma unroll
        for (int k = 0; k < 8; ++k)
            s += reinterpret_cast<const float*>(&psumA[k * 64 + gp])[comp];
        rnArr[tid] = 1.0f / fmaxf(sqrtf(s), 1e-12f);
    } else if (tid < 160) {
        const int rr = tid - 128;
        const int gp = rr >> 1, comp = rr & 1;
        float s = 0.f;
#pragma unroll
        for (int k = 0; k < 8; ++k)
            s += reinterpret_cast<const float*>(&psumB[k * 16 + gp])[comp];
        rnArr[tid] = 1.0f / fmaxf(sqrtf(s), 1e-12f);
    }
    __syncthreads();   // bar2: rnArr visible; psum dead (ud writes now safe)

    // ---- banded MFMA (nrt split) + compact key pack ----
    {
        float rq[4];
#pragma unroll
        for (int j = 0; j < 4; ++j) rq[j] = rnArr[90 + qt * 16 + lk * 4 + j];
        const int q0 = qt * 16 + lk * 4;
#pragma unroll
        for (int i = 0; i < 4; ++i) {
            if (i < nrt) {
                const int rto = h * 4 + i;
                const int rbase = qt * 16 + rto * 16;
                const ushort* bp = &sb[(size_t)(rbase + lr) * SD2 + lk * 8];
                bf16x8 b0 = *reinterpret_cast<const bf16x8*>(bp);
                bf16x8 b1 = *reinterpret_cast<const bf16x8*>(bp + 32);
                f32x4 acc = {0.f, 0.f, 0.f, 0.f};
                acc = __builtin_amdgcn_mfma_f32_16x16x32_bf16(a0, b0, acc, 0, 0, 0);
                acc = __builtin_amdgcn_mfma_f32_16x16x32_bf16(a1, b1, acc, 0, 0, 0);
                const int r = rbase + lr;
                const float rnr = rnArr[r];
#pragma unroll
                for (int j = 0; j < 4; ++j) {
                    int rel = r - (q0 + j) - 1;      // window offset wofs
                    if (rel >= 0 && rel <= 89) {
                        float p = acc[j] * rq[j] * rnr;
                        float dist = 2.0f - 2.0f * p;
                        uint32_t uu = __float_as_uint(dist);
                        uu = (uu & 0x80000000u) ? ~uu : (uu | 0x80000000u);
                        ud[(q0 + j) * UD2 + rel] = (uu & 0xFFFFFF80u) | (uint32_t)rel;
                    }
                }
            }
        }
    }
    __syncthreads();   // bar3: keys visible

    // ---- selection: 8 lanes per query, 9 rounds of masked-min extraction ----
    {
        const int ql = l >> 3;             // 0..7
        const int s  = l & 7;              // 0..7
        const int q  = (w << 3) | ql;      // 0..63
        const int n  = n0 + q;

        uint32_t key[12];
#pragma unroll
        for (int t = 0; t < 12; ++t) {
            int wofs = s + 8 * t;          // window offset 0..95
            int m = n - 89 + wofs;
            bool ok = (wofs <= 89) && (m >= 0);
            uint32_t raw = ud[q * UD2 + (ok ? wofs : 0)];
            key[t] = ok ? raw : 0xFFFFFFFFu;
        }

        uint32_t prev = 0;
        int omKeep = n;
        int om8 = n;
#pragma unroll
        for (int j = 0; j < KK; ++j) {
            uint32_t mn = 0xFFFFFFFFu;
#pragma unroll
            for (int t = 0; t < 12; ++t) {
                uint32_t cand = (key[t] > prev) ? key[t] : 0xFFFFFFFFu;
                mn = (cand < mn) ? cand : mn;
            }
            uint32_t o;
            o = (uint32_t)__shfl_xor((int)mn, 1); mn = (o < mn) ? o : mn;
            o = (uint32_t)__shfl_xor((int)mn, 2); mn = (o < mn) ? o : mn;
            o = (uint32_t)__shfl_xor((int)mn, 4); mn = (o < mn) ? o : mn;
            int om = (mn == 0xFFFFFFFFu) ? n : (n - 89 + (int)(mn & 127u));
            if (j < 8) {
                if (s == j) omKeep = om;
            } else {
                om8 = om;
            }
            prev = mn;
        }

        const int base0 = (b * NPTS + n) * KK;
        const int base1 = NB * NPTS * KK + base0;
        out[base0 + s] = omKeep;           // 8 coalesced lanes per query
        out[base1 + s] = n;
        if (s == 0) {
            out[base0 + 8] = om8;
            out[base1 + 8] = n;
        }
    }
}

extern "C" void kernel_launch(void* const* d_in, const int* in_sizes, int n_in,
                              void* d_out, int out_size, void* d_ws, size_t ws_size,
                              hipStream_t stream) {
    const float* x = (const float*)d_in[0];
    int* out = (int*)d_out;
    knn_fused<<<NB * (NPTS / BQ), 512, 0, stream>>>(x, out);
}